// Round 13
// baseline (573.445 us; speedup 1.0000x reference)
//
#include <hip/hip_runtime.h>
#include <hip/hip_fp16.h>

#define D 146
#define AS 160      // fp16 activation row stride in halves (320B; cols 146..159 zero)
#define HWS 80      // activation row stride in half2
#define NG 100
#define BN_EPS 1e-5f

typedef _Float16 half8 __attribute__((ext_vector_type(8)));
typedef float f32x4 __attribute__((ext_vector_type(4)));

// ---------------- pack weights into MFMA B-fragment order ----------------
__global__ void packw_k(const float* __restrict__ Wemb, const float* __restrict__ Ws,
                        __half* __restrict__ Wf)
{
    int idx = blockIdx.x * 256 + threadIdx.x;
    if (idx >= 5 * 5 * 10 * 64 * 8) return;
    int i8 = idx & 7;
    int l  = (idx >> 3) & 63;
    int t  = (idx >> 9) % 10;
    int s  = (idx / (8 * 64 * 10)) % 5;
    int m  = idx / (8 * 64 * 10 * 5);
    int k = s * 32 + ((l >> 4) << 3) + i8;
    int c = t * 16 + (l & 15);
    float v = 0.0f;
    if (k < D && c < D) {
        const float* Wsrc = (m == 0) ? Wemb : (Ws + (size_t)(m - 1) * D * D);
        v = Wsrc[k * D + c];
    }
    Wf[idx] = __float2half(v);
}

// ---------------- nodes fp32 [N][146] -> fp16 [N][160] ----------------
__global__ void cvtnodes_k(const float* __restrict__ nodes, __half2* __restrict__ out2, int N)
{
    int idx = blockIdx.x * 256 + threadIdx.x;
    if (idx >= N * HWS) return;
    int r = idx / HWS, j = idx % HWS;
    int c = 2 * j;
    float v0 = (c < D) ? nodes[(size_t)r * D + c] : 0.0f;
    float v1 = (c + 1 < D) ? nodes[(size_t)r * D + c + 1] : 0.0f;
    out2[idx] = __floats2half2_rn(v0, v1);
}

// ---------------- degree histograms ----------------
__global__ void deg_k(const int* __restrict__ src, const int* __restrict__ dst,
                      int* __restrict__ co, int* __restrict__ ci, int E)
{
    int e = blockIdx.x * 256 + threadIdx.x;
    if (e >= E) return;
    atomicAdd(&co[src[e]], 1);
    atomicAdd(&ci[dst[e]], 1);
}

// ---------------- parallel exclusive scan over PADDED in-degrees ----------------
__global__ __launch_bounds__(256) void pscan1_k(const int* __restrict__ cnt,
                                                int* __restrict__ bsum, int N)
{
    __shared__ int lds[256];
    int t = blockIdx.x * 256 + threadIdx.x;
    lds[threadIdx.x] = (t < N) ? ((cnt[t] + 7) & ~7) : 0;
    __syncthreads();
    for (int s = 128; s > 0; s >>= 1) {
        if (threadIdx.x < s) lds[threadIdx.x] += lds[threadIdx.x + s];
        __syncthreads();
    }
    if (threadIdx.x == 0) bsum[blockIdx.x] = lds[0];
}

__global__ __launch_bounds__(256) void pscan2_k(const int* __restrict__ bsum,
                                                int* __restrict__ boff, int nb)
{
    __shared__ int lds[256];
    int t = threadIdx.x;
    int v = (t < nb) ? bsum[t] : 0;
    lds[t] = v;
    __syncthreads();
    for (int off = 1; off < 256; off <<= 1) {
        int u = (t >= off) ? lds[t - off] : 0;
        __syncthreads();
        lds[t] += u;
        __syncthreads();
    }
    boff[t] = lds[t] - v;
}

// pscan3 + degree-norm rsq fused
__global__ __launch_bounds__(256) void pscan3_k(const int* __restrict__ cnt,
                                                const int* __restrict__ boff,
                                                int* __restrict__ rowptr,
                                                int* __restrict__ cursor,
                                                const int* __restrict__ co,
                                                float* __restrict__ ns,
                                                float* __restrict__ nd, int N)
{
    __shared__ int lds[256];
    int t = blockIdx.x * 256 + threadIdx.x;
    int cv = (t < N) ? cnt[t] : 0;
    int v = (cv + 7) & ~7;
    if (t >= N) v = 0;
    lds[threadIdx.x] = v;
    __syncthreads();
    for (int off = 1; off < 256; off <<= 1) {
        int u = (threadIdx.x >= off) ? lds[threadIdx.x - off] : 0;
        __syncthreads();
        lds[threadIdx.x] += u;
        __syncthreads();
    }
    if (t < N) {
        int r = boff[blockIdx.x] + lds[threadIdx.x] - v;
        rowptr[t] = r;
        cursor[t] = r;
        ns[t] = rsqrtf(fmaxf((float)co[t], 1.0f));
        nd[t] = rsqrtf(fmaxf((float)cv, 1.0f));
    }
}

// ---------------- CSR fill ----------------
__global__ void csrfill_k(const int* __restrict__ src, const int* __restrict__ dst,
                          int* __restrict__ cursor, int* __restrict__ esrc, int E)
{
    int e = blockIdx.x * 256 + threadIdx.x;
    if (e >= E) return;
    int pos = atomicAdd(&cursor[dst[e]], 1);
    esrc[pos] = src[e];
}

// ---------------- finalize: rowptr[N], pad-fill, edge-balanced wave partition ----------------
__global__ void finalize_k(const int* __restrict__ cnt, int* __restrict__ rowptr,
                           int* __restrict__ esrc, int* __restrict__ wstart,
                           int N, int NW)
{
    int idx = blockIdx.x * 256 + threadIdx.x;
    int Epad = rowptr[N - 1] + ((cnt[N - 1] + 7) & ~7);
    if (idx == 0) rowptr[N] = Epad;
    if (idx < N) {
        int b = rowptr[idx] + cnt[idx];
        int ee = rowptr[idx] + ((cnt[idx] + 7) & ~7);
        for (int i = b; i < ee; ++i) esrc[i] = N;   // row N is all zeros
    }
    if (idx <= NW) {
        if (idx == NW) wstart[NW] = N;
        else if (idx == 0) wstart[0] = 0;
        else {
            long long target = (long long)Epad * idx / NW;
            int lo = 0, hi = N;                       // first n with rowptr[n] > target
            while (lo < hi) {
                int mid = (lo + hi) >> 1;
                if ((long long)rowptr[mid] <= target) lo = mid + 1; else hi = mid;
            }
            wstart[idx] = lo - 1;
        }
    }
}

// ---------------- MFMA GEMM: per wave 32 rows x 160 cols; rowscale applied to A-frags ----------------
// bias != null (embedding): OUT16 = fp16(acc + bias), all 160 cols.
// bias == null (layer):     OUT16 = fp16(acc), cols < 146; A scaled by rowscale in-register.
__global__ __launch_bounds__(256) void gemm_mfma(
    const __half* __restrict__ A16, const __half* __restrict__ Wf,
    __half* __restrict__ OUT16, int nrows,
    const float* __restrict__ rowscale, const float* __restrict__ bias)
{
    int lane = threadIdx.x & 63, wave = threadIdx.x >> 6;
    int m0 = blockIdx.x * 128 + wave * 32;
    int ar0 = min(m0 + (lane & 15), nrows - 1);
    int ar1 = min(m0 + 16 + (lane & 15), nrows - 1);
    int ak = (lane >> 4) * 8;
    _Float16 s0 = (_Float16)(rowscale ? rowscale[ar0] : 1.0f);
    _Float16 s1 = (_Float16)(rowscale ? rowscale[ar1] : 1.0f);

    f32x4 acc0[10] = {};
    f32x4 acc1[10] = {};
    const half8* WfV = reinterpret_cast<const half8*>(Wf);
#pragma unroll
    for (int s = 0; s < 5; ++s) {
        half8 a0 = *reinterpret_cast<const half8*>(&A16[(size_t)ar0 * AS + s * 32 + ak]);
        half8 a1 = *reinterpret_cast<const half8*>(&A16[(size_t)ar1 * AS + s * 32 + ak]);
#pragma unroll
        for (int i = 0; i < 8; ++i) { a0[i] *= s0; a1[i] *= s1; }
        const half8* wrow = WfV + (size_t)(s * 10) * 64 + lane;
#pragma unroll
        for (int t = 0; t < 10; ++t) {
            half8 b = wrow[(size_t)t * 64];
            acc0[t] = __builtin_amdgcn_mfma_f32_16x16x32_f16(a0, b, acc0[t], 0, 0, 0);
            acc1[t] = __builtin_amdgcn_mfma_f32_16x16x32_f16(a1, b, acc1[t], 0, 0, 0);
        }
    }

    int ccol = lane & 15;
    bool evenl = (lane & 1) == 0;
    bool embed = (bias != nullptr);
#pragma unroll
    for (int tile = 0; tile < 2; ++tile) {
        int rbase = m0 + tile * 16 + (lane >> 4) * 4;
        f32x4* acc = tile ? acc1 : acc0;
#pragma unroll
        for (int t = 0; t < 10; ++t) {
            int c = t * 16 + ccol;
            float bv = (embed && c < D) ? bias[c] : 0.0f;
#pragma unroll
            for (int j = 0; j < 4; ++j) {
                int r = rbase + j;
                float v = acc[t][j] + bv;
                float vn = __shfl_xor(v, 1);
                if (evenl && r < nrows && (embed || c < D))
                    *reinterpret_cast<__half2*>(&OUT16[(size_t)r * AS + c]) =
                        __floats2half2_rn(v, vn);
            }
        }
    }
}

// ---------------- CSR gather-sum (fp16, 8-block padded, edge-balanced) + p1 + BN stats ----------------
__global__ __launch_bounds__(256) void agg_k(
    const __half2* __restrict__ hW2, const int* __restrict__ esrc,
    const int* __restrict__ rowptr, const int* __restrict__ wstart,
    const float* __restrict__ nd, const float* __restrict__ sn,
    const float* __restrict__ bias,
    __half2* __restrict__ hpre2, float* __restrict__ stats, int N)
{
    __shared__ float rs[4][D];
    __shared__ float rq[4][D];
    int lane = threadIdx.x & 63, wave = threadIdx.x >> 6;
    int w = blockIdx.x * 4 + wave;
    int w0 = wstart[w], w1 = wstart[w + 1];

    bool v1 = lane < 9;
    int j0 = lane, j1 = 64 + lane;
    int c0 = 2 * lane, c1 = 128 + 2 * lane;
    int c1m = v1 ? c1 : 0;
    float b00 = bias[c0], b01 = bias[c0 + 1];
    float b10 = bias[c1m], b11 = bias[c1m + 1];
    float s00 = 0, s01 = 0, s10 = 0, s11 = 0, q00 = 0, q01 = 0, q10 = 0, q11 = 0;

    int e = (w0 < w1) ? rowptr[w0] : 0;
    for (int n = w0; n < w1; ++n) {
        int ee = rowptr[n + 1];
        float a00 = 0, a01 = 0, a10 = 0, a11 = 0;
        for (; e < ee; e += 8) {
            int4 i0 = *reinterpret_cast<const int4*>(&esrc[e]);
            int4 i1 = *reinterpret_cast<const int4*>(&esrc[e + 4]);
            const __half2* p0 = hW2 + (size_t)i0.x * HWS;
            const __half2* p1 = hW2 + (size_t)i0.y * HWS;
            const __half2* p2 = hW2 + (size_t)i0.z * HWS;
            const __half2* p3 = hW2 + (size_t)i0.w * HWS;
            const __half2* p4 = hW2 + (size_t)i1.x * HWS;
            const __half2* p5 = hW2 + (size_t)i1.y * HWS;
            const __half2* p6 = hW2 + (size_t)i1.z * HWS;
            const __half2* p7 = hW2 + (size_t)i1.w * HWS;
            float2 f0 = __half22float2(p0[j0]);
            float2 f1 = __half22float2(p1[j0]);
            float2 f2 = __half22float2(p2[j0]);
            float2 f3 = __half22float2(p3[j0]);
            float2 f4 = __half22float2(p4[j0]);
            float2 f5 = __half22float2(p5[j0]);
            float2 f6 = __half22float2(p6[j0]);
            float2 f7 = __half22float2(p7[j0]);
            a00 += ((f0.x + f1.x) + (f2.x + f3.x)) + ((f4.x + f5.x) + (f6.x + f7.x));
            a01 += ((f0.y + f1.y) + (f2.y + f3.y)) + ((f4.y + f5.y) + (f6.y + f7.y));
            if (v1) {
                float2 g0 = __half22float2(p0[j1]);
                float2 g1 = __half22float2(p1[j1]);
                float2 g2 = __half22float2(p2[j1]);
                float2 g3 = __half22float2(p3[j1]);
                float2 g4 = __half22float2(p4[j1]);
                float2 g5 = __half22float2(p5[j1]);
                float2 g6 = __half22float2(p6[j1]);
                float2 g7 = __half22float2(p7[j1]);
                a10 += ((g0.x + g1.x) + (g2.x + g3.x)) + ((g4.x + g5.x) + (g6.x + g7.x));
                a11 += ((g0.y + g1.y) + (g2.y + g3.y)) + ((g4.y + g5.y) + (g6.y + g7.y));
            }
        }
        float ndv = nd[n], snv = sn[n];
        float h00 = (a00 * ndv + b00) * snv;
        float h01 = (a01 * ndv + b01) * snv;
        hpre2[(size_t)n * (D / 2) + j0] = __floats2half2_rn(h00, h01);
        s00 += h00; q00 = fmaf(h00, h00, q00);
        s01 += h01; q01 = fmaf(h01, h01, q01);
        if (v1) {
            float h10 = (a10 * ndv + b10) * snv;
            float h11 = (a11 * ndv + b11) * snv;
            hpre2[(size_t)n * (D / 2) + j1] = __floats2half2_rn(h10, h11);
            s10 += h10; q10 = fmaf(h10, h10, q10);
            s11 += h11; q11 = fmaf(h11, h11, q11);
        }
    }
    rs[wave][c0] = s00; rs[wave][c0 + 1] = s01;
    rq[wave][c0] = q00; rq[wave][c0 + 1] = q01;
    if (v1) {
        rs[wave][c1] = s10; rs[wave][c1 + 1] = s11;
        rq[wave][c1] = q10; rq[wave][c1 + 1] = q11;
    }
    __syncthreads();
    for (int cc = threadIdx.x; cc < D; cc += 256) {
        atomicAdd(&stats[cc], rs[0][cc] + rs[1][cc] + rs[2][cc] + rs[3][cc]);
        atomicAdd(&stats[D + cc], rq[0][cc] + rq[1][cc] + rq[2][cc] + rq[3][cc]);
    }
}

// ---------------- h16 += relu(bn(hpre)); hg pooling (bnfin fused) ----------------
// storeh == 0 on last layer: skip h16 store (dead after pooling).
__global__ __launch_bounds__(256) void p2hg_k(
    __half2* __restrict__ h2, const __half2* __restrict__ hpre2,
    const float* __restrict__ stats, const float* __restrict__ gamma,
    const float* __restrict__ beta, const float* __restrict__ sn,
    const int* __restrict__ gid, float* __restrict__ hg, int N, int storeh)
{
    int lane = threadIdx.x & 63, wave = threadIdx.x >> 6;
    int per = (N + gridDim.x - 1) / gridDim.x;
    int n0 = blockIdx.x * per;
    int n1 = min(N, n0 + per);
    int wper = (per + 3) >> 2;
    int w0 = min(n1, n0 + wave * wper);
    int w1 = min(n1, w0 + wper);
    if (w0 >= w1) return;

    bool v1 = lane < 9;
    int j0 = lane, j1 = 64 + lane;
    int c0 = 2 * lane, c1 = 128 + 2 * lane;
    int c1m = v1 ? c1 : 0;
    float inv = 1.0f / (float)N;
    float m00 = stats[c0] * inv,     m01 = stats[c0 + 1] * inv;
    float m10 = stats[c1m] * inv,    m11 = stats[c1m + 1] * inv;
    float v00 = fmaxf(stats[D + c0] * inv - m00 * m00, 0.0f);
    float v01 = fmaxf(stats[D + c0 + 1] * inv - m01 * m01, 0.0f);
    float v10 = fmaxf(stats[D + c1m] * inv - m10 * m10, 0.0f);
    float v11 = fmaxf(stats[D + c1m + 1] * inv - m11 * m11, 0.0f);
    float r00 = rsqrtf(v00 + BN_EPS), r01 = rsqrtf(v01 + BN_EPS);
    float r10 = rsqrtf(v10 + BN_EPS), r11 = rsqrtf(v11 + BN_EPS);
    float g00 = gamma[c0], g01 = gamma[c0 + 1], t00 = beta[c0], t01 = beta[c0 + 1];
    float g10 = gamma[c1m], g11 = gamma[c1m + 1], t10 = beta[c1m], t11 = beta[c1m + 1];

    int g = gid[w0];
    float a00 = 0, a01 = 0, a10 = 0, a11 = 0;
    for (int n = w0; n < w1; ++n) {
        int gr = gid[n];
        if (gr != g) {
            atomicAdd(&hg[(size_t)g * D + c0], a00);
            atomicAdd(&hg[(size_t)g * D + c0 + 1], a01);
            if (v1) {
                atomicAdd(&hg[(size_t)g * D + c1], a10);
                atomicAdd(&hg[(size_t)g * D + c1 + 1], a11);
            }
            a00 = a01 = a10 = a11 = 0;
            g = gr;
        }
        float w2 = sn[n]; w2 *= w2;
        float2 hv = __half22float2(h2[(size_t)n * HWS + j0]);
        float2 p0 = __half22float2(hpre2[(size_t)n * (D / 2) + j0]);
        float x0 = hv.x + fmaxf((p0.x - m00) * r00 * g00 + t00, 0.0f);
        float x1 = hv.y + fmaxf((p0.y - m01) * r01 * g01 + t01, 0.0f);
        if (storeh) h2[(size_t)n * HWS + j0] = __floats2half2_rn(x0, x1);
        a00 = fmaf(x0, w2, a00);
        a01 = fmaf(x1, w2, a01);
        if (v1) {
            float2 hv1 = __half22float2(h2[(size_t)n * HWS + j1]);
            float2 p1 = __half22float2(hpre2[(size_t)n * (D / 2) + j1]);
            float x2 = hv1.x + fmaxf((p1.x - m10) * r10 * g10 + t10, 0.0f);
            float x3 = hv1.y + fmaxf((p1.y - m11) * r11 * g11 + t11, 0.0f);
            if (storeh) h2[(size_t)n * HWS + j1] = __floats2half2_rn(x2, x3);
            a10 = fmaf(x2, w2, a10);
            a11 = fmaf(x3, w2, a11);
        }
    }
    atomicAdd(&hg[(size_t)g * D + c0], a00);
    atomicAdd(&hg[(size_t)g * D + c0 + 1], a01);
    if (v1) {
        atomicAdd(&hg[(size_t)g * D + c1], a10);
        atomicAdd(&hg[(size_t)g * D + c1 + 1], a11);
    }
}

// ---------------- fused MLP readout: one block per graph ----------------
__global__ __launch_bounds__(128) void readout_k(
    const float* __restrict__ hg,
    const float* __restrict__ W0, const float* __restrict__ b0,
    const float* __restrict__ W1, const float* __restrict__ b1,
    const float* __restrict__ W2, const float* __restrict__ b2,
    float* __restrict__ out)
{
    __shared__ float hl[D];
    __shared__ float z1[73];
    __shared__ float z2[36];
    int g = blockIdx.x;
    int t = threadIdx.x;
    for (int i = t; i < D; i += 128) hl[i] = hg[(size_t)g * D + i];
    __syncthreads();
    if (t < 73) {
        float s = b0[t];
        for (int k = 0; k < D; ++k) s = fmaf(hl[k], W0[k * 73 + t], s);
        z1[t] = fmaxf(s, 0.0f);
    }
    __syncthreads();
    if (t < 36) {
        float s = b1[t];
        for (int k = 0; k < 73; ++k) s = fmaf(z1[k], W1[k * 36 + t], s);
        z2[t] = fmaxf(s, 0.0f);
    }
    __syncthreads();
    if (t < 10) {
        float s = b2[t];
        for (int k = 0; k < 36; ++k) s = fmaf(z2[k], W2[k * 10 + t], s);
        out[g * 10 + t] = s;
    }
}

extern "C" void kernel_launch(void* const* d_in, const int* in_sizes, int n_in,
                              void* d_out, int out_size, void* d_ws, size_t ws_size,
                              hipStream_t stream)
{
    const float* nodes  = (const float*)d_in[0];
    const float* snorm  = (const float*)d_in[1];
    const float* Wemb   = (const float*)d_in[2];
    const float* bemb   = (const float*)d_in[3];
    const float* Ws     = (const float*)d_in[4];
    const float* bs     = (const float*)d_in[5];
    const float* gammas = (const float*)d_in[6];
    const float* betas  = (const float*)d_in[7];
    const float* Wr0    = (const float*)d_in[8];
    const float* br0    = (const float*)d_in[9];
    const float* Wr1    = (const float*)d_in[10];
    const float* br1    = (const float*)d_in[11];
    const float* Wr2    = (const float*)d_in[12];
    const float* br2    = (const float*)d_in[13];
    const int*   src    = (const int*)d_in[14];
    const int*   dst    = (const int*)d_in[15];
    const int*   gid    = (const int*)d_in[16];

    int N = in_sizes[0] / D;
    int E = in_sizes[14];
    int nb = (N + 255) / 256;
    const int NWF = 5 * 5 * 10 * 64 * 8;   // packed weight halves
    int Ecap = E + 8 * ((N + 7) & ~7);     // padded edge capacity
    const int AGB = 1024;                  // agg blocks (proven optimum)
    const int NW = AGB * 4;                // agg waves

    float* ws = (float*)d_ws;
    size_t off = 0;
    // contiguous zero region: stats | hg | cnt_out | cnt_in  (one memset)
    float* stats = ws + off; off += 4 * 4 * D;
    float* hg    = ws + off; off += (size_t)NG * D;
    int* cnt_out = (int*)(ws + off); off += N;
    int* cnt_in  = (int*)(ws + off); off += N;
    size_t zbytes = (16 * D + (size_t)NG * D + 2 * (size_t)N) * 4;
    float* nsrc  = ws + off; off += N;
    float* ndst  = ws + off; off += N;
    int* rowptr  = (int*)(ws + off); off += N + 4;
    int* cursor  = (int*)(ws + off); off += N;
    int* esrc    = (int*)(ws + off); off += Ecap;
    int* bsum    = (int*)(ws + off); off += 256;
    int* boff    = (int*)(ws + off); off += 256;
    int* wstart  = (int*)(ws + off); off += NW + 4;
    off = (off + 3) & ~(size_t)3;                        // 16B-align the half region
    __half* Wf      = (__half*)(ws + off); off += NWF / 2;
    __half* h16     = (__half*)(ws + off); off += (size_t)N * AS / 2;
    __half* nodes16 = (__half*)(ws + off);               // aliases hW16 (disjoint lifetime)
    __half* hW16    = (__half*)(ws + off); off += (size_t)(N + 1) * AS / 2;  // +1 zero row
    __half* hpre16  = (__half*)(ws + off); off += (size_t)N * D / 2;

    // setup
    hipMemsetAsync(stats, 0, zbytes, stream);
    hipMemsetAsync(hW16 + (size_t)N * AS, 0, AS * sizeof(__half), stream);   // zero row N
    packw_k<<<(NWF + 255) / 256, 256, 0, stream>>>(Wemb, Ws, Wf);
    cvtnodes_k<<<(N * HWS + 255) / 256, 256, 0, stream>>>(nodes, (__half2*)nodes16, N);
    deg_k<<<(E + 255) / 256, 256, 0, stream>>>(src, dst, cnt_out, cnt_in, E);
    pscan1_k<<<nb, 256, 0, stream>>>(cnt_in, bsum, N);
    pscan2_k<<<1, 256, 0, stream>>>(bsum, boff, nb);
    pscan3_k<<<nb, 256, 0, stream>>>(cnt_in, boff, rowptr, cursor, cnt_out, nsrc, ndst, N);
    csrfill_k<<<(E + 255) / 256, 256, 0, stream>>>(src, dst, cursor, esrc, E);
    finalize_k<<<nb, 256, 0, stream>>>(cnt_in, rowptr, esrc, wstart, N, NW);

    int gblk = (N + 127) / 128;
    // embedding: h16 = fp16(nodes@Wemb + b) [N][160]
    gemm_mfma<<<gblk, 256, 0, stream>>>(nodes16, Wf, h16, N, nullptr, bemb);

    for (int l = 0; l < 4; ++l) {
        float* st = stats + (size_t)l * 4 * D;
        // hW = (h*nsrc)@W  (row scale applied to A-fragments in-register)
        gemm_mfma<<<gblk, 256, 0, stream>>>(h16, Wf + (size_t)(l + 1) * (NWF / 5),
                                            hW16, N, nsrc, nullptr);
        agg_k<<<AGB, 256, 0, stream>>>((const __half2*)hW16, esrc, rowptr, wstart, ndst, snorm,
                                       bs + (size_t)l * D, (__half2*)hpre16, st, N);
        p2hg_k<<<2048, 256, 0, stream>>>((__half2*)h16, (const __half2*)hpre16, st,
                                         gammas + (size_t)l * D, betas + (size_t)l * D,
                                         snorm, gid, hg, N, (l < 3) ? 1 : 0);
    }

    readout_k<<<NG, 128, 0, stream>>>(hg, Wr0, br0, Wr1, br1, Wr2, br2, (float*)d_out);
}

// Round 14
// 549.104 us; speedup vs baseline: 1.0443x; 1.0443x over previous
//
#include <hip/hip_runtime.h>
#include <hip/hip_fp16.h>

#define D 146
#define AS 160      // fp16 activation row stride in halves (320B; cols 146..159 zero)
#define HWS 80      // activation row stride in half2
#define NG 100
#define BN_EPS 1e-5f

typedef _Float16 half8 __attribute__((ext_vector_type(8)));
typedef float f32x4 __attribute__((ext_vector_type(4)));

// ---------------- pack weights into MFMA B-fragment order ----------------
__global__ void packw_k(const float* __restrict__ Wemb, const float* __restrict__ Ws,
                        __half* __restrict__ Wf)
{
    int idx = blockIdx.x * 256 + threadIdx.x;
    if (idx >= 5 * 5 * 10 * 64 * 8) return;
    int i8 = idx & 7;
    int l  = (idx >> 3) & 63;
    int t  = (idx >> 9) % 10;
    int s  = (idx / (8 * 64 * 10)) % 5;
    int m  = idx / (8 * 64 * 10 * 5);
    int k = s * 32 + ((l >> 4) << 3) + i8;
    int c = t * 16 + (l & 15);
    float v = 0.0f;
    if (k < D && c < D) {
        const float* Wsrc = (m == 0) ? Wemb : (Ws + (size_t)(m - 1) * D * D);
        v = Wsrc[k * D + c];
    }
    Wf[idx] = __float2half(v);
}

// ---------------- nodes fp32 [N][146] -> fp16 [N][160] ----------------
__global__ void cvtnodes_k(const float* __restrict__ nodes, __half2* __restrict__ out2, int N)
{
    int idx = blockIdx.x * 256 + threadIdx.x;
    if (idx >= N * HWS) return;
    int r = idx / HWS, j = idx % HWS;
    int c = 2 * j;
    float v0 = (c < D) ? nodes[(size_t)r * D + c] : 0.0f;
    float v1 = (c + 1 < D) ? nodes[(size_t)r * D + c + 1] : 0.0f;
    out2[idx] = __floats2half2_rn(v0, v1);
}

// ---------------- degree histograms ----------------
__global__ void deg_k(const int* __restrict__ src, const int* __restrict__ dst,
                      int* __restrict__ co, int* __restrict__ ci, int E)
{
    int e = blockIdx.x * 256 + threadIdx.x;
    if (e >= E) return;
    atomicAdd(&co[src[e]], 1);
    atomicAdd(&ci[dst[e]], 1);
}

// ---------------- parallel exclusive scan over PADDED in-degrees ----------------
__global__ __launch_bounds__(256) void pscan1_k(const int* __restrict__ cnt,
                                                int* __restrict__ bsum, int N)
{
    __shared__ int lds[256];
    int t = blockIdx.x * 256 + threadIdx.x;
    lds[threadIdx.x] = (t < N) ? ((cnt[t] + 7) & ~7) : 0;
    __syncthreads();
    for (int s = 128; s > 0; s >>= 1) {
        if (threadIdx.x < s) lds[threadIdx.x] += lds[threadIdx.x + s];
        __syncthreads();
    }
    if (threadIdx.x == 0) bsum[blockIdx.x] = lds[0];
}

__global__ __launch_bounds__(256) void pscan2_k(const int* __restrict__ bsum,
                                                int* __restrict__ boff, int nb)
{
    __shared__ int lds[256];
    int t = threadIdx.x;
    int v = (t < nb) ? bsum[t] : 0;
    lds[t] = v;
    __syncthreads();
    for (int off = 1; off < 256; off <<= 1) {
        int u = (t >= off) ? lds[t - off] : 0;
        __syncthreads();
        lds[t] += u;
        __syncthreads();
    }
    boff[t] = lds[t] - v;
}

// pscan3 + degree-norm rsq fused
__global__ __launch_bounds__(256) void pscan3_k(const int* __restrict__ cnt,
                                                const int* __restrict__ boff,
                                                int* __restrict__ rowptr,
                                                int* __restrict__ cursor,
                                                const int* __restrict__ co,
                                                float* __restrict__ ns,
                                                float* __restrict__ nd, int N)
{
    __shared__ int lds[256];
    int t = blockIdx.x * 256 + threadIdx.x;
    int cv = (t < N) ? cnt[t] : 0;
    int v = (t < N) ? ((cv + 7) & ~7) : 0;
    lds[threadIdx.x] = v;
    __syncthreads();
    for (int off = 1; off < 256; off <<= 1) {
        int u = (threadIdx.x >= off) ? lds[threadIdx.x - off] : 0;
        __syncthreads();
        lds[threadIdx.x] += u;
        __syncthreads();
    }
    if (t < N) {
        int r = boff[blockIdx.x] + lds[threadIdx.x] - v;
        rowptr[t] = r;
        cursor[t] = r;
        ns[t] = rsqrtf(fmaxf((float)co[t], 1.0f));
        nd[t] = rsqrtf(fmaxf((float)cv, 1.0f));
    }
}

// ---------------- CSR fill ----------------
__global__ void csrfill_k(const int* __restrict__ src, const int* __restrict__ dst,
                          int* __restrict__ cursor, int* __restrict__ esrc, int E)
{
    int e = blockIdx.x * 256 + threadIdx.x;
    if (e >= E) return;
    int pos = atomicAdd(&cursor[dst[e]], 1);
    esrc[pos] = src[e];
}

// ---------------- finalize: rowptr[N], pad-fill, edge-balanced wave partition ----------------
__global__ void finalize_k(const int* __restrict__ cnt, int* __restrict__ rowptr,
                           int* __restrict__ esrc, int* __restrict__ wstart,
                           int N, int NW)
{
    int idx = blockIdx.x * 256 + threadIdx.x;
    int Epad = rowptr[N - 1] + ((cnt[N - 1] + 7) & ~7);
    if (idx == 0) rowptr[N] = Epad;
    if (idx < N) {
        int b = rowptr[idx] + cnt[idx];
        int ee = rowptr[idx] + ((cnt[idx] + 7) & ~7);
        for (int i = b; i < ee; ++i) esrc[i] = N;   // row N is all zeros
    }
    if (idx <= NW) {
        if (idx == NW) wstart[NW] = N;
        else if (idx == 0) wstart[0] = 0;
        else {
            long long target = (long long)Epad * idx / NW;
            int lo = 0, hi = N;                       // first n with rowptr[n] > target
            while (lo < hi) {
                int mid = (lo + hi) >> 1;
                if ((long long)rowptr[mid] <= target) lo = mid + 1; else hi = mid;
            }
            wstart[idx] = lo - 1;
        }
    }
}

// ---------------- MFMA GEMM: per wave 32 rows x 160 cols (2 M-tiles share B-frags) ----------------
// H16 set (embedding): H16 = fp16(acc+bias) all 160 cols, C16h = fp16((acc+bias)*rowscale).
// H16 null (layer):    C16h = fp16(acc) cols<146 only.
// Epilogue packs adjacent-lane fp16 values into half2 stores via shfl_xor(.,1).
__global__ __launch_bounds__(256) void gemm_mfma(
    const __half* __restrict__ A16, const __half* __restrict__ Wf,
    __half* __restrict__ C16h, __half* __restrict__ H16, int nrows,
    const float* __restrict__ rowscale, const float* __restrict__ bias)
{
    int lane = threadIdx.x & 63, wave = threadIdx.x >> 6;
    int m0 = blockIdx.x * 128 + wave * 32;
    int ar0 = min(m0 + (lane & 15), nrows - 1);
    int ar1 = min(m0 + 16 + (lane & 15), nrows - 1);
    int ak = (lane >> 4) * 8;

    f32x4 acc0[10] = {};
    f32x4 acc1[10] = {};
    const half8* WfV = reinterpret_cast<const half8*>(Wf);
#pragma unroll
    for (int s = 0; s < 5; ++s) {
        half8 a0 = *reinterpret_cast<const half8*>(&A16[(size_t)ar0 * AS + s * 32 + ak]);
        half8 a1 = *reinterpret_cast<const half8*>(&A16[(size_t)ar1 * AS + s * 32 + ak]);
        const half8* wrow = WfV + (size_t)(s * 10) * 64 + lane;
#pragma unroll
        for (int t = 0; t < 10; ++t) {
            half8 b = wrow[(size_t)t * 64];
            acc0[t] = __builtin_amdgcn_mfma_f32_16x16x32_f16(a0, b, acc0[t], 0, 0, 0);
            acc1[t] = __builtin_amdgcn_mfma_f32_16x16x32_f16(a1, b, acc1[t], 0, 0, 0);
        }
    }

    int ccol = lane & 15;
    bool evenl = (lane & 1) == 0;
#pragma unroll
    for (int tile = 0; tile < 2; ++tile) {
        int rbase = m0 + tile * 16 + (lane >> 4) * 4;
        f32x4* acc = tile ? acc1 : acc0;
        if (H16) {
            float rsv[4];
#pragma unroll
            for (int j = 0; j < 4; ++j) {
                int r = rbase + j;
                rsv[j] = (r < nrows) ? rowscale[r] : 0.0f;
            }
#pragma unroll
            for (int t = 0; t < 10; ++t) {
                int c = t * 16 + ccol;
                float bv = (c < D) ? bias[c] : 0.0f;
#pragma unroll
                for (int j = 0; j < 4; ++j) {
                    int r = rbase + j;
                    float v = acc[t][j] + bv;
                    float vn = __shfl_xor(v, 1);
                    if (evenl && r < nrows) {
                        *reinterpret_cast<__half2*>(&H16[(size_t)r * AS + c]) =
                            __floats2half2_rn(v, vn);
                        *reinterpret_cast<__half2*>(&C16h[(size_t)r * AS + c]) =
                            __floats2half2_rn(v * rsv[j], vn * rsv[j]);
                    }
                }
            }
        } else {
#pragma unroll
            for (int t = 0; t < 10; ++t) {
                int c = t * 16 + ccol;
#pragma unroll
                for (int j = 0; j < 4; ++j) {
                    int r = rbase + j;
                    float v = acc[t][j];
                    float vn = __shfl_xor(v, 1);
                    if (evenl && c < D && r < nrows)
                        *reinterpret_cast<__half2*>(&C16h[(size_t)r * AS + c]) =
                            __floats2half2_rn(v, vn);
                }
            }
        }
    }
}

// ---------------- CSR gather-sum (fp16, 8-block padded, edge-balanced) + p1 + BN stats ----------------
__global__ __launch_bounds__(256) void agg_k(
    const __half2* __restrict__ hW2, const int* __restrict__ esrc,
    const int* __restrict__ rowptr, const int* __restrict__ wstart,
    const float* __restrict__ nd, const float* __restrict__ sn,
    const float* __restrict__ bias,
    __half2* __restrict__ hpre2, float* __restrict__ stats, int N)
{
    __shared__ float rs[4][D];
    __shared__ float rq[4][D];
    int lane = threadIdx.x & 63, wave = threadIdx.x >> 6;
    int w = blockIdx.x * 4 + wave;
    int w0 = wstart[w], w1 = wstart[w + 1];

    bool v1 = lane < 9;
    int j0 = lane, j1 = 64 + lane;
    int c0 = 2 * lane, c1 = 128 + 2 * lane;
    int c1m = v1 ? c1 : 0;
    float b00 = bias[c0], b01 = bias[c0 + 1];
    float b10 = bias[c1m], b11 = bias[c1m + 1];
    float s00 = 0, s01 = 0, s10 = 0, s11 = 0, q00 = 0, q01 = 0, q10 = 0, q11 = 0;

    int e = (w0 < w1) ? rowptr[w0] : 0;
    for (int n = w0; n < w1; ++n) {
        int ee = rowptr[n + 1];
        float a00 = 0, a01 = 0, a10 = 0, a11 = 0;
        for (; e < ee; e += 8) {
            int4 i0 = *reinterpret_cast<const int4*>(&esrc[e]);
            int4 i1 = *reinterpret_cast<const int4*>(&esrc[e + 4]);
            const __half2* p0 = hW2 + (size_t)i0.x * HWS;
            const __half2* p1 = hW2 + (size_t)i0.y * HWS;
            const __half2* p2 = hW2 + (size_t)i0.z * HWS;
            const __half2* p3 = hW2 + (size_t)i0.w * HWS;
            const __half2* p4 = hW2 + (size_t)i1.x * HWS;
            const __half2* p5 = hW2 + (size_t)i1.y * HWS;
            const __half2* p6 = hW2 + (size_t)i1.z * HWS;
            const __half2* p7 = hW2 + (size_t)i1.w * HWS;
            float2 f0 = __half22float2(p0[j0]);
            float2 f1 = __half22float2(p1[j0]);
            float2 f2 = __half22float2(p2[j0]);
            float2 f3 = __half22float2(p3[j0]);
            float2 f4 = __half22float2(p4[j0]);
            float2 f5 = __half22float2(p5[j0]);
            float2 f6 = __half22float2(p6[j0]);
            float2 f7 = __half22float2(p7[j0]);
            a00 += ((f0.x + f1.x) + (f2.x + f3.x)) + ((f4.x + f5.x) + (f6.x + f7.x));
            a01 += ((f0.y + f1.y) + (f2.y + f3.y)) + ((f4.y + f5.y) + (f6.y + f7.y));
            if (v1) {
                float2 g0 = __half22float2(p0[j1]);
                float2 g1 = __half22float2(p1[j1]);
                float2 g2 = __half22float2(p2[j1]);
                float2 g3 = __half22float2(p3[j1]);
                float2 g4 = __half22float2(p4[j1]);
                float2 g5 = __half22float2(p5[j1]);
                float2 g6 = __half22float2(p6[j1]);
                float2 g7 = __half22float2(p7[j1]);
                a10 += ((g0.x + g1.x) + (g2.x + g3.x)) + ((g4.x + g5.x) + (g6.x + g7.x));
                a11 += ((g0.y + g1.y) + (g2.y + g3.y)) + ((g4.y + g5.y) + (g6.y + g7.y));
            }
        }
        float ndv = nd[n], snv = sn[n];
        float h00 = (a00 * ndv + b00) * snv;
        float h01 = (a01 * ndv + b01) * snv;
        hpre2[(size_t)n * (D / 2) + j0] = __floats2half2_rn(h00, h01);
        s00 += h00; q00 = fmaf(h00, h00, q00);
        s01 += h01; q01 = fmaf(h01, h01, q01);
        if (v1) {
            float h10 = (a10 * ndv + b10) * snv;
            float h11 = (a11 * ndv + b11) * snv;
            hpre2[(size_t)n * (D / 2) + j1] = __floats2half2_rn(h10, h11);
            s10 += h10; q10 = fmaf(h10, h10, q10);
            s11 += h11; q11 = fmaf(h11, h11, q11);
        }
    }
    rs[wave][c0] = s00; rs[wave][c0 + 1] = s01;
    rq[wave][c0] = q00; rq[wave][c0 + 1] = q01;
    if (v1) {
        rs[wave][c1] = s10; rs[wave][c1 + 1] = s11;
        rq[wave][c1] = q10; rq[wave][c1 + 1] = q11;
    }
    __syncthreads();
    for (int cc = threadIdx.x; cc < D; cc += 256) {
        atomicAdd(&stats[cc], rs[0][cc] + rs[1][cc] + rs[2][cc] + rs[3][cc]);
        atomicAdd(&stats[D + cc], rq[0][cc] + rq[1][cc] + rq[2][cc] + rq[3][cc]);
    }
}

// ---------------- h16 += relu(bn(hpre)); hs16 = h*nsrc; hg pooling (bnfin fused) ----------------
// hs2 == nullptr => last layer: skip h16 and hs16 stores (dead after pooling).
__global__ __launch_bounds__(256) void p2hg_k(
    __half2* __restrict__ h2, const __half2* __restrict__ hpre2,
    const float* __restrict__ stats, const float* __restrict__ gamma,
    const float* __restrict__ beta, const float* __restrict__ sn,
    const float* __restrict__ nsrc, const int* __restrict__ gid,
    __half2* __restrict__ hs2, float* __restrict__ hg, int N)
{
    int lane = threadIdx.x & 63, wave = threadIdx.x >> 6;
    int per = (N + gridDim.x - 1) / gridDim.x;
    int n0 = blockIdx.x * per;
    int n1 = min(N, n0 + per);
    int wper = (per + 3) >> 2;
    int w0 = min(n1, n0 + wave * wper);
    int w1 = min(n1, w0 + wper);
    if (w0 >= w1) return;

    bool v1 = lane < 9;
    bool wr = (hs2 != nullptr);
    int j0 = lane, j1 = 64 + lane;
    int c0 = 2 * lane, c1 = 128 + 2 * lane;
    int c1m = v1 ? c1 : 0;
    float inv = 1.0f / (float)N;
    float m00 = stats[c0] * inv,     m01 = stats[c0 + 1] * inv;
    float m10 = stats[c1m] * inv,    m11 = stats[c1m + 1] * inv;
    float v00 = fmaxf(stats[D + c0] * inv - m00 * m00, 0.0f);
    float v01 = fmaxf(stats[D + c0 + 1] * inv - m01 * m01, 0.0f);
    float v10 = fmaxf(stats[D + c1m] * inv - m10 * m10, 0.0f);
    float v11 = fmaxf(stats[D + c1m + 1] * inv - m11 * m11, 0.0f);
    float r00 = rsqrtf(v00 + BN_EPS), r01 = rsqrtf(v01 + BN_EPS);
    float r10 = rsqrtf(v10 + BN_EPS), r11 = rsqrtf(v11 + BN_EPS);
    float g00 = gamma[c0], g01 = gamma[c0 + 1], t00 = beta[c0], t01 = beta[c0 + 1];
    float g10 = gamma[c1m], g11 = gamma[c1m + 1], t10 = beta[c1m], t11 = beta[c1m + 1];

    int g = gid[w0];
    float a00 = 0, a01 = 0, a10 = 0, a11 = 0;
    for (int n = w0; n < w1; ++n) {
        int gr = gid[n];
        if (gr != g) {
            atomicAdd(&hg[(size_t)g * D + c0], a00);
            atomicAdd(&hg[(size_t)g * D + c0 + 1], a01);
            if (v1) {
                atomicAdd(&hg[(size_t)g * D + c1], a10);
                atomicAdd(&hg[(size_t)g * D + c1 + 1], a11);
            }
            a00 = a01 = a10 = a11 = 0;
            g = gr;
        }
        float ns = nsrc[n];
        float w2 = sn[n]; w2 *= w2;
        float2 hv = __half22float2(h2[(size_t)n * HWS + j0]);
        float2 p0 = __half22float2(hpre2[(size_t)n * (D / 2) + j0]);
        float x0 = hv.x + fmaxf((p0.x - m00) * r00 * g00 + t00, 0.0f);
        float x1 = hv.y + fmaxf((p0.y - m01) * r01 * g01 + t01, 0.0f);
        if (wr) {
            h2[(size_t)n * HWS + j0] = __floats2half2_rn(x0, x1);
            hs2[(size_t)n * HWS + j0] = __floats2half2_rn(x0 * ns, x1 * ns);
        }
        a00 = fmaf(x0, w2, a00);
        a01 = fmaf(x1, w2, a01);
        if (v1) {
            float2 hv1 = __half22float2(h2[(size_t)n * HWS + j1]);
            float2 p1 = __half22float2(hpre2[(size_t)n * (D / 2) + j1]);
            float x2 = hv1.x + fmaxf((p1.x - m10) * r10 * g10 + t10, 0.0f);
            float x3 = hv1.y + fmaxf((p1.y - m11) * r11 * g11 + t11, 0.0f);
            if (wr) {
                h2[(size_t)n * HWS + j1] = __floats2half2_rn(x2, x3);
                hs2[(size_t)n * HWS + j1] = __floats2half2_rn(x2 * ns, x3 * ns);
            }
            a10 = fmaf(x2, w2, a10);
            a11 = fmaf(x3, w2, a11);
        }
    }
    atomicAdd(&hg[(size_t)g * D + c0], a00);
    atomicAdd(&hg[(size_t)g * D + c0 + 1], a01);
    if (v1) {
        atomicAdd(&hg[(size_t)g * D + c1], a10);
        atomicAdd(&hg[(size_t)g * D + c1 + 1], a11);
    }
}

// ---------------- fused MLP readout: one block per graph ----------------
__global__ __launch_bounds__(128) void readout_k(
    const float* __restrict__ hg,
    const float* __restrict__ W0, const float* __restrict__ b0,
    const float* __restrict__ W1, const float* __restrict__ b1,
    const float* __restrict__ W2, const float* __restrict__ b2,
    float* __restrict__ out)
{
    __shared__ float hl[D];
    __shared__ float z1[73];
    __shared__ float z2[36];
    int g = blockIdx.x;
    int t = threadIdx.x;
    for (int i = t; i < D; i += 128) hl[i] = hg[(size_t)g * D + i];
    __syncthreads();
    if (t < 73) {
        float s = b0[t];
        for (int k = 0; k < D; ++k) s = fmaf(hl[k], W0[k * 73 + t], s);
        z1[t] = fmaxf(s, 0.0f);
    }
    __syncthreads();
    if (t < 36) {
        float s = b1[t];
        for (int k = 0; k < 73; ++k) s = fmaf(z1[k], W1[k * 36 + t], s);
        z2[t] = fmaxf(s, 0.0f);
    }
    __syncthreads();
    if (t < 10) {
        float s = b2[t];
        for (int k = 0; k < 36; ++k) s = fmaf(z2[k], W2[k * 10 + t], s);
        out[g * 10 + t] = s;
    }
}

extern "C" void kernel_launch(void* const* d_in, const int* in_sizes, int n_in,
                              void* d_out, int out_size, void* d_ws, size_t ws_size,
                              hipStream_t stream)
{
    const float* nodes  = (const float*)d_in[0];
    const float* snorm  = (const float*)d_in[1];
    const float* Wemb   = (const float*)d_in[2];
    const float* bemb   = (const float*)d_in[3];
    const float* Ws     = (const float*)d_in[4];
    const float* bs     = (const float*)d_in[5];
    const float* gammas = (const float*)d_in[6];
    const float* betas  = (const float*)d_in[7];
    const float* Wr0    = (const float*)d_in[8];
    const float* br0    = (const float*)d_in[9];
    const float* Wr1    = (const float*)d_in[10];
    const float* br1    = (const float*)d_in[11];
    const float* Wr2    = (const float*)d_in[12];
    const float* br2    = (const float*)d_in[13];
    const int*   src    = (const int*)d_in[14];
    const int*   dst    = (const int*)d_in[15];
    const int*   gid    = (const int*)d_in[16];

    int N = in_sizes[0] / D;
    int E = in_sizes[14];
    int nb = (N + 255) / 256;
    const int NWF = 5 * 5 * 10 * 64 * 8;   // packed weight halves
    int Ecap = E + 8 * ((N + 7) & ~7);     // padded edge capacity
    const int AGB = 1024;                  // agg blocks (proven optimum)
    const int NW = AGB * 4;                // agg waves

    float* ws = (float*)d_ws;
    size_t off = 0;
    // contiguous zero region: stats | hg | cnt_out | cnt_in  (one memset)
    float* stats = ws + off; off += 4 * 4 * D;
    float* hg    = ws + off; off += (size_t)NG * D;
    int* cnt_out = (int*)(ws + off); off += N;
    int* cnt_in  = (int*)(ws + off); off += N;
    size_t zbytes = (16 * D + (size_t)NG * D + 2 * (size_t)N) * 4;
    float* nsrc  = ws + off; off += N;
    float* ndst  = ws + off; off += N;
    int* rowptr  = (int*)(ws + off); off += N + 4;
    int* cursor  = (int*)(ws + off); off += N;
    int* esrc    = (int*)(ws + off); off += Ecap;
    int* bsum    = (int*)(ws + off); off += 256;
    int* boff    = (int*)(ws + off); off += 256;
    int* wstart  = (int*)(ws + off); off += NW + 4;
    off = (off + 3) & ~(size_t)3;                        // 16B-align the half region
    __half* Wf      = (__half*)(ws + off); off += NWF / 2;
    __half* h16     = (__half*)(ws + off); off += (size_t)N * AS / 2;
    __half* hs16    = (__half*)(ws + off); off += (size_t)N * AS / 2;
    __half* nodes16 = (__half*)(ws + off);               // aliases hW16 (disjoint lifetime)
    __half* hW16    = (__half*)(ws + off); off += (size_t)(N + 1) * AS / 2;  // +1 zero row
    __half* hpre16  = (__half*)(ws + off); off += (size_t)N * D / 2;

    // setup
    hipMemsetAsync(stats, 0, zbytes, stream);
    hipMemsetAsync(hW16 + (size_t)N * AS, 0, AS * sizeof(__half), stream);   // zero row N
    packw_k<<<(NWF + 255) / 256, 256, 0, stream>>>(Wemb, Ws, Wf);
    cvtnodes_k<<<(N * HWS + 255) / 256, 256, 0, stream>>>(nodes, (__half2*)nodes16, N);
    deg_k<<<(E + 255) / 256, 256, 0, stream>>>(src, dst, cnt_out, cnt_in, E);
    pscan1_k<<<nb, 256, 0, stream>>>(cnt_in, bsum, N);
    pscan2_k<<<1, 256, 0, stream>>>(bsum, boff, nb);
    pscan3_k<<<nb, 256, 0, stream>>>(cnt_in, boff, rowptr, cursor, cnt_out, nsrc, ndst, N);
    csrfill_k<<<(E + 255) / 256, 256, 0, stream>>>(src, dst, cursor, esrc, E);
    finalize_k<<<nb, 256, 0, stream>>>(cnt_in, rowptr, esrc, wstart, N, NW);

    int gblk = (N + 127) / 128;
    // embedding: h16 = fp16(nodes@Wemb + b), hs16 = fp16(h*nsrc) [N][160]
    gemm_mfma<<<gblk, 256, 0, stream>>>(nodes16, Wf, hs16, h16, N, nsrc, bemb);

    for (int l = 0; l < 4; ++l) {
        float* st = stats + (size_t)l * 4 * D;
        gemm_mfma<<<gblk, 256, 0, stream>>>(hs16, Wf + (size_t)(l + 1) * (NWF / 5),
                                            hW16, nullptr, N, nullptr, nullptr);
        agg_k<<<AGB, 256, 0, stream>>>((const __half2*)hW16, esrc, rowptr, wstart, ndst, snorm,
                                       bs + (size_t)l * D, (__half2*)hpre16, st, N);
        p2hg_k<<<2048, 256, 0, stream>>>((__half2*)h16, (const __half2*)hpre16, st,
                                         gammas + (size_t)l * D, betas + (size_t)l * D,
                                         snorm, nsrc, gid,
                                         (l == 3) ? nullptr : (__half2*)hs16, hg, N);
    }

    readout_k<<<NG, 128, 0, stream>>>(hg, Wr0, br0, Wr1, br1, Wr2, br2, (float*)d_out);
}